// Round 11
// baseline (277.324 us; speedup 1.0000x reference)
//
#include <hip/hip_runtime.h>
#include <hip/hip_bf16.h>
#include <hip/hip_fp16.h>
#include <cstdint>
#include <cstddef>

#define NN 4096
#define FD 256
#define WPR 64  // 64-bit words per adjacency row

typedef __attribute__((ext_vector_type(8))) unsigned short ushort8v;
typedef __attribute__((ext_vector_type(4))) unsigned short ushort4v;
typedef __attribute__((ext_vector_type(8))) short short8;
typedef __attribute__((ext_vector_type(4))) float float4v;

#define C1 30.0f
#define C2 0.3f    // 0.01 * C1

static __device__ __forceinline__ unsigned short f2bf(float x) {
    union { float f; unsigned int u; } v; v.f = x;
    unsigned int r = v.u + 0x7FFFu + ((v.u >> 16) & 1u);
    return (unsigned short)(r >> 16);
}

static __device__ __forceinline__ short8 as_s8(ushort8v v) {
    union { ushort8v u; short8 s; } x; x.u = v; return x.s;
}

// ---------------- fused setup: pack adj + cvt input + cvt weights + zero f1f2 ----------------
__global__ __launch_bounds__(256) void setup(const int* __restrict__ adj,
                                             const float* __restrict__ input,
                                             const float* __restrict__ W0, const float* __restrict__ W1,
                                             const float* __restrict__ W2, const float* __restrict__ W3,
                                             unsigned long long* __restrict__ bits,
                                             unsigned short* __restrict__ hb,
                                             unsigned short* __restrict__ Wbt,
                                             float* __restrict__ f1f2) {
    const int b = blockIdx.x;
    const int t = threadIdx.x;
    if (b < 4096) {
        const int wave = t >> 6, lane = t & 63;
        const int* arow = adj + (size_t)b * NN;
        #pragma unroll
        for (int it = 0; it < NN / 256; ++it) {
            int j = it * 256 + wave * 64 + lane;
            unsigned long long m = __ballot(arow[j] > 0);
            if (lane == 0) bits[(size_t)b * WPR + (it * 4 + wave)] = m;
        }
        hb[(size_t)b * 256 + t] = f2bf(input[(size_t)b * 256 + t]);
    } else if (b < 5120) {
        int idx = (b - 4096) * 256 + t;
        int mat = idx >> 16;
        int within = idx & 65535;
        int n = within >> 8, k = within & 255;
        const float* W = (mat == 0) ? W0 : (mat == 1) ? W1 : (mat == 2) ? W2 : W3;
        Wbt[idx] = f2bf(W[k * 256 + n]);
    } else {
        #pragma unroll
        for (int i = 0; i < 24; ++i) {
            int pos = i * 1024 + (b - 5120) * 256 + t;
            f1f2[pos] = 0.f;
        }
    }
}

// ---------------- projection GEMM: 32x64 tiles, grid 512 (layers 0/1 only) ----------------
__global__ __launch_bounds__(256) void proj_gemm(const unsigned short* __restrict__ A,
                                                 const unsigned short* __restrict__ Bt,
                                                 const float* __restrict__ av,
                                                 float* __restrict__ f1f2,
                                                 unsigned short* __restrict__ Cbt,
                                                 unsigned short* __restrict__ Crow) {
    const int t = threadIdx.x;
    const int bm = blockIdx.x >> 2, bn = blockIdx.x & 3;
    const int m0 = bm * 32, n0 = bn * 64;
    __shared__ unsigned short As[32 * 264];
    __shared__ unsigned short Bs[64 * 264];
    const int lane = t & 63, wave = t >> 6;
    const int wm = (wave >> 1) * 16, wn = (wave & 1) * 32;
    const int g = lane >> 4, ml = lane & 15;
    {
        int ar = t >> 3, ac0 = (t & 7) * 8;
        #pragma unroll
        for (int i = 0; i < 4; ++i) {
            int col = ac0 + i * 64;
            *(ushort8v*)&As[ar * 264 + col] = *(const ushort8v*)&A[(size_t)(m0 + ar) * 256 + col];
        }
        int br = t >> 2, bc0 = (t & 3) * 8;
        #pragma unroll
        for (int i = 0; i < 8; ++i) {
            int col = bc0 + i * 32;
            *(ushort8v*)&Bs[br * 264 + col] = *(const ushort8v*)&Bt[(size_t)(n0 + br) * 256 + col];
        }
    }
    __syncthreads();
    float4v acc[2] = {{0.f,0.f,0.f,0.f},{0.f,0.f,0.f,0.f}};
    #pragma unroll
    for (int kk = 0; kk < 256; kk += 32) {
        const int kc = kk + g * 8;
        short8 a = as_s8(*(const ushort8v*)&As[(wm + ml) * 264 + kc]);
        #pragma unroll
        for (int fn = 0; fn < 2; ++fn) {
            short8 b = as_s8(*(const ushort8v*)&Bs[(wn + fn * 16 + ml) * 264 + kc]);
            acc[fn] = __builtin_amdgcn_mfma_f32_16x16x32_bf16(a, b, acc[fn], 0, 0, 0);
        }
    }

    const int rb = wm + g * 4;
    if (Crow) {
        #pragma unroll
        for (int fn = 0; fn < 2; ++fn)
            #pragma unroll
            for (int r = 0; r < 4; ++r)
                Crow[(size_t)(m0 + rb + r) * 256 + n0 + wn + fn * 16 + ml] = f2bf(acc[fn][r]);
    }

    if (f1f2) {
        float a1c[2], a2c[2];
        #pragma unroll
        for (int fn = 0; fn < 2; ++fn) {
            a1c[fn] = av[n0 + wn + fn * 16 + ml];
            a2c[fn] = av[256 + n0 + wn + fn * 16 + ml];
        }
        #pragma unroll
        for (int r = 0; r < 4; ++r) {
            float s1 = acc[0][r] * a1c[0] + acc[1][r] * a1c[1];
            float s2 = acc[0][r] * a2c[0] + acc[1][r] * a2c[1];
            #pragma unroll
            for (int off = 1; off < 16; off <<= 1) {
                s1 += __shfl_xor(s1, off, 64);
                s2 += __shfl_xor(s2, off, 64);
            }
            if (ml == 0) {
                int row = m0 + rb + r;
                atomicAdd(&f1f2[row], s1);
                atomicAdd(&f1f2[4096 + row], s2);
            }
        }
    }

    if (Cbt) {
        unsigned short* T = As;
        __syncthreads();
        #pragma unroll
        for (int fn = 0; fn < 2; ++fn)
            #pragma unroll
            for (int r = 0; r < 4; ++r)
                T[(wn + fn * 16 + ml) * 40 + rb + r] = f2bf(acc[fn][r]);
        __syncthreads();
        const int tr = t >> 2, tc = (t & 3) * 8;
        *(ushort8v*)&Cbt[(size_t)(n0 + tr) * 4096 + m0 + tc] = *(const ushort8v*)&T[tr * 40 + tc];
    }
}

// ---------------- per-row coefficients + global exp tables ----------------
__global__ __launch_bounds__(256) void rowcoef(const unsigned long long* __restrict__ bits,
                                               const float* __restrict__ f1f2,
                                               float4* __restrict__ rowco,
                                               float2* __restrict__ tab2g) {
    __shared__ float2 tl[4096];
    const int t = threadIdx.x;
    const float* f2p = f1f2 + 4096;
    #pragma unroll
    for (int i = 0; i < 16; ++i) {
        float v = f2p[i * 256 + t];
        float2 pr = make_float2(__expf(v - C1), __expf(0.01f * v - C2));
        tl[i * 256 + t] = pr;
        if (blockIdx.x == 0) tab2g[i * 256 + t] = pr;
    }
    __syncthreads();
    const int lane = t & 63, wave = t >> 6;
    for (int rr = 0; rr < 2; ++rr) {
        const int row = blockIdx.x * 8 + wave * 2 + rr;
        const unsigned long long wl = bits[(size_t)row * WPR + lane];
        const float f1r = f1f2[row];
        const float th = __expf(-f1r - C1);
        float mx = 0.f, S1 = 0.f, S2 = 0.f;
        #pragma unroll 16
        for (int b = 0; b < 64; ++b) {
            unsigned long long w = __shfl(wl, b, 64);
            bool bit = (w >> lane) & 1ULL;
            float2 v = tl[b * 64 + lane];
            float ebm = bit ? v.x : 0.f;
            mx = fmaxf(mx, ebm);
            bool cond = v.x > th;
            S1 += (bit && cond)  ? v.x : 0.f;
            S2 += (bit && !cond) ? v.y : 0.f;
        }
        #pragma unroll
        for (int off = 1; off < 64; off <<= 1) {
            mx = fmaxf(mx, __shfl_xor(mx, off, 64));
            S1 += __shfl_xor(S1, off, 64);
            S2 += __shfl_xor(S2, off, 64);
        }
        if (lane == 0) {
            float M  = C1 + __logf(mx);
            float fm_ = f1r + M;
            float m  = fm_ > 0.f ? fm_ : 0.01f * fm_;    // lrelu
            float alpha = __expf(fminf(f1r + C1 - m, 60.f));
            float gamma = __expf(fminf(0.01f * (f1r + C1) - m, 60.f));
            float inv = 1.0f / (alpha * S1 + gamma * S2);
            rowco[row] = make_float4(alpha * inv, gamma * inv, th, 0.f);
        }
    }
}

// ---------------- attention GEMM (r10, unchanged): hoisted loads, dbuf B, 1 barrier/step ----------------
template<int NSTEPS>
__global__ __launch_bounds__(256, 3) void att_gemm(const unsigned long long* __restrict__ bits,
                                                   const float4* __restrict__ rowco,
                                                   const float* __restrict__ tab2f,
                                                   const unsigned short* __restrict__ Bt,  // Whbt [256][4096]
                                                   unsigned short* __restrict__ parth) {
    const int t = threadIdx.x;
    const int bm = blockIdx.x & 31;
    const int bn = (blockIdx.x >> 5) & 1;
    const int ks = blockIdx.x >> 6;
    const int m0 = bm * 128, n0 = bn * 128;
    const int k0 = ks * (NSTEPS * 32);
    __shared__ unsigned short Bs[2][128 * 40];
    const int lane = t & 63, wave = t >> 6;
    const int g = lane >> 4, ml = lane & 15;
    const int srow = t >> 1, skh = (t & 1) * 16;
    const unsigned short* bsrc = Bt + (size_t)(n0 + srow) * 4096 + skh;

    float pA[2], pG[2];
    unsigned long long wpre[2][NSTEPS / 2];
    #pragma unroll
    for (int fm = 0; fm < 2; ++fm) {
        int row = m0 + wave * 32 + fm * 16 + ml;
        float4 rc = rowco[row];
        pA[fm] = rc.x; pG[fm] = rc.y;
        const unsigned long long* brow = bits + (size_t)row * WPR + (k0 >> 6);
        #pragma unroll
        for (int w = 0; w < NSTEPS / 2; ++w) wpre[fm][w] = brow[w];
    }

    float4v acc[2][8];
    #pragma unroll
    for (int i = 0; i < 2; ++i)
        #pragma unroll
        for (int j = 0; j < 8; ++j) acc[i][j] = (float4v){0.f, 0.f, 0.f, 0.f};

    float4v tq0, tq1, tq2, tq3;
    {
        ushort8v b0 = *(const ushort8v*)&bsrc[k0];
        ushort8v b1 = *(const ushort8v*)&bsrc[k0 + 8];
        const float4v* q = (const float4v*)&tab2f[2 * (k0 + g * 8)];
        tq0 = q[0]; tq1 = q[1]; tq2 = q[2]; tq3 = q[3];
        *(ushort8v*)&Bs[0][srow * 40 + skh]     = b0;
        *(ushort8v*)&Bs[0][srow * 40 + skh + 8] = b1;
    }
    __syncthreads();

    #pragma unroll
    for (int i = 0; i < NSTEPS; ++i) {
        const int kk = k0 + i * 32;
        const int p = i & 1;
        ushort8v nb0, nb1;
        float4v nt0, nt1, nt2, nt3;
        if (i + 1 < NSTEPS) {
            nb0 = *(const ushort8v*)&bsrc[kk + 32];
            nb1 = *(const ushort8v*)&bsrc[kk + 40];
            const float4v* q = (const float4v*)&tab2f[2 * (kk + 32 + g * 8)];
            nt0 = q[0]; nt1 = q[1]; nt2 = q[2]; nt3 = q[3];
        }
        const int sh = (i & 1) * 32 + g * 8;
        short8 afr[2];
        #pragma unroll
        for (int fm = 0; fm < 2; ++fm) {
            unsigned int wh = (unsigned int)(wpre[fm][i >> 1] >> sh);
            ushort8v af;
            #pragma unroll
            for (int jj = 0; jj < 4; ++jj) {
                float4v v = (jj == 0) ? tq0 : (jj == 1) ? tq1 : (jj == 2) ? tq2 : tq3;
                float x0 = fmaxf(pA[fm] * v[0], pG[fm] * v[1]);
                float x1 = fmaxf(pA[fm] * v[2], pG[fm] * v[3]);
                x0 = ((wh >> (2 * jj)) & 1u)     ? x0 : 0.f;
                x1 = ((wh >> (2 * jj + 1)) & 1u) ? x1 : 0.f;
                union { __hip_bfloat162 b2; unsigned int u; } cv;
                cv.b2 = __float22bfloat162_rn(make_float2(x0, x1));
                ((unsigned int*)&af)[jj] = cv.u;
            }
            afr[fm] = as_s8(af);
        }
        #pragma unroll
        for (int fn = 0; fn < 8; ++fn) {
            short8 b = as_s8(*(const ushort8v*)&Bs[p][(fn * 16 + ml) * 40 + g * 8]);
            acc[0][fn] = __builtin_amdgcn_mfma_f32_16x16x32_bf16(afr[0], b, acc[0][fn], 0, 0, 0);
            acc[1][fn] = __builtin_amdgcn_mfma_f32_16x16x32_bf16(afr[1], b, acc[1][fn], 0, 0, 0);
        }
        if (i + 1 < NSTEPS) {
            *(ushort8v*)&Bs[1 - p][srow * 40 + skh]     = nb0;
            *(ushort8v*)&Bs[1 - p][srow * 40 + skh + 8] = nb1;
            __syncthreads();
            tq0 = nt0; tq1 = nt1; tq2 = nt2; tq3 = nt3;
        }
    }

    unsigned short* pbase = parth + ((size_t)ks << 20) + (size_t)(bm * 2 + bn) * 16384;
    #pragma unroll
    for (int fm = 0; fm < 2; ++fm)
        #pragma unroll
        for (int fn = 0; fn < 8; ++fn) {
            ushort4v v4;
            #pragma unroll
            for (int r = 0; r < 4; ++r) {
                __half h = __float2half(acc[fm][fn][r]);
                v4[r] = *(unsigned short*)&h;
            }
            *(ushort4v*)&pbase[((wave * 16 + fm * 8 + fn) * 64 + lane) * 4] = v4;
        }
}

// ---------------- fused reduce(partials)+ELU -> h in LDS -> proj GEMM -> Whbt + f1f2 ----------------
// Block bm handles output rows [bm*16, bm*16+16), all 256 cols. Grid 256.
template<int NS>
__global__ __launch_bounds__(256) void fused_rp(const unsigned short* __restrict__ parth,
                                                const unsigned short* __restrict__ Bt,   // Wbt [256n][256k]
                                                const float* __restrict__ av,            // attention vec [512]
                                                float* __restrict__ f1f2,
                                                unsigned short* __restrict__ Cbt) {      // Whbt [256][4096]
    const int t = threadIdx.x;
    const int m0 = blockIdx.x * 16;
    __shared__ unsigned short hA[16 * 280];     // 16 rows x 256 bf16, stride 280 (16B-aligned rows)
    __shared__ unsigned short T[256 * 24];      // transpose buffer

    // ---- phase 1: reduce 16 partial elems per thread (coalesced permuted chunks) ----
    const int bmP = m0 >> 7;
    const int wavea = (m0 >> 5) & 3;
    const int fmP = (m0 >> 4) & 1;
    const int bn = t >> 7, fnc = (t >> 4) & 7;
    const int widx = wavea * 16 + fmP * 8 + fnc;
    const size_t cbase = (size_t)(bmP * 2 + bn) * 16384 + (size_t)widx * 256 + (t & 15) * 16;
    float s[16];
    #pragma unroll
    for (int e = 0; e < 16; ++e) s[e] = 0.f;
    #pragma unroll
    for (int sp = 0; sp < NS; ++sp) {
        const unsigned short* p = &parth[((size_t)sp << 20) + cbase];
        ushort8v v0 = *(const ushort8v*)p;
        ushort8v v1 = *(const ushort8v*)(p + 8);
        #pragma unroll
        for (int e = 0; e < 8; ++e) {
            unsigned short u0 = v0[e], u1 = v1[e];
            s[e]     += __half2float(*(__half*)&u0);
            s[8 + e] += __half2float(*(__half*)&u1);
        }
    }
    // ELU + scatter into hA[row][col]
    const int gq = (t & 15) >> 2;
    const int colb = bn * 128 + fnc * 16 + (t & 3) * 4;
    #pragma unroll
    for (int r = 0; r < 4; ++r) {
        ushort4v w4;
        #pragma unroll
        for (int c = 0; c < 4; ++c) {
            float x = s[c * 4 + r];
            x = x > 0.f ? x : (__expf(x) - 1.f);
            w4[c] = f2bf(x);
        }
        *(ushort4v*)&hA[(gq * 4 + r) * 280 + colb] = w4;
    }
    __syncthreads();

    // ---- phase 2: GEMM 16x256 @ 256: wave owns n-cols [wave*64, +64) ----
    const int lane = t & 63, wave = t >> 6;
    const int g = lane >> 4, ml = lane & 15;
    float4v acc[4] = {{0.f,0.f,0.f,0.f},{0.f,0.f,0.f,0.f},{0.f,0.f,0.f,0.f},{0.f,0.f,0.f,0.f}};
    #pragma unroll
    for (int kk = 0; kk < 256; kk += 32) {
        short8 a = as_s8(*(const ushort8v*)&hA[ml * 280 + kk + g * 8]);
        #pragma unroll
        for (int fn = 0; fn < 4; ++fn) {
            short8 b = as_s8(*(const ushort8v*)&Bt[(size_t)(wave * 64 + fn * 16 + ml) * 256 + kk + g * 8]);
            acc[fn] = __builtin_amdgcn_mfma_f32_16x16x32_bf16(a, b, acc[fn], 0, 0, 0);
        }
    }

    // ---- epilogue A: f1/f2 atomics ----
    {
        float a1c[4], a2c[4];
        #pragma unroll
        for (int fn = 0; fn < 4; ++fn) {
            int col = wave * 64 + fn * 16 + ml;
            a1c[fn] = av[col];
            a2c[fn] = av[256 + col];
        }
        #pragma unroll
        for (int r = 0; r < 4; ++r) {
            float s1 = acc[0][r] * a1c[0] + acc[1][r] * a1c[1] + acc[2][r] * a1c[2] + acc[3][r] * a1c[3];
            float s2 = acc[0][r] * a2c[0] + acc[1][r] * a2c[1] + acc[2][r] * a2c[2] + acc[3][r] * a2c[3];
            #pragma unroll
            for (int off = 1; off < 16; off <<= 1) {
                s1 += __shfl_xor(s1, off, 64);
                s2 += __shfl_xor(s2, off, 64);
            }
            if (ml == 0) {
                int row = m0 + g * 4 + r;
                atomicAdd(&f1f2[row], s1);
                atomicAdd(&f1f2[4096 + row], s2);
            }
        }
    }

    // ---- epilogue B: Whbt via LDS transpose ----
    #pragma unroll
    for (int fn = 0; fn < 4; ++fn) {
        int nl = wave * 64 + fn * 16 + ml;
        ushort4v v4;
        #pragma unroll
        for (int r = 0; r < 4; ++r) v4[r] = f2bf(acc[fn][r]);
        *(ushort4v*)&T[nl * 24 + g * 4] = v4;
    }
    __syncthreads();
    {
        const int tn = t >> 1, half = t & 1;
        #pragma unroll
        for (int pass = 0; pass < 2; ++pass) {
            int n = pass * 128 + tn;
            *(ushort8v*)&Cbt[(size_t)n * 4096 + m0 + half * 8] = *(const ushort8v*)&T[n * 24 + half * 8];
        }
    }
}

// ---------------- final reduce: partials -> ELU -> fp32 out ----------------
template<int NS>
__global__ __launch_bounds__(256) void reduce_out(const unsigned short* __restrict__ parth,
                                                  float* __restrict__ outf) {
    const int flat = (blockIdx.x * 256 + threadIdx.x) * 8;
    float s[8] = {0.f, 0.f, 0.f, 0.f, 0.f, 0.f, 0.f, 0.f};
    #pragma unroll
    for (int sp = 0; sp < NS; ++sp) {
        ushort8v v = *(const ushort8v*)&parth[((size_t)sp << 20) + flat];
        #pragma unroll
        for (int j = 0; j < 8; ++j) {
            unsigned short u = v[j];
            s[j] += __half2float(*(__half*)&u);
        }
    }
    const int tile  = flat >> 14;
    const int inner = flat & 16383;
    const int widx = inner >> 8;
    const int ls   = (inner >> 2) & 63;
    const int bm = tile >> 1, bn = tile & 1;
    const int wavea = widx >> 4, fm = (widx >> 3) & 1, fn = widx & 7;
    const int g = ls >> 4, ml = ls & 15;
    const int row0 = bm * 128 + wavea * 32 + fm * 16 + g * 4;
    const int col  = bn * 128 + fn * 16 + ml;
    #pragma unroll
    for (int r = 0; r < 4; ++r) {
        float x0 = s[r];
        float x1 = s[4 + r];
        x0 = x0 > 0.f ? x0 : (__expf(x0) - 1.f);
        x1 = x1 > 0.f ? x1 : (__expf(x1) - 1.f);
        *(float2*)&outf[(size_t)(row0 + r) * 256 + col] = make_float2(x0, x1);
    }
}

static void launch_att(int SPLIT, const unsigned long long* bits, const float4* rowco,
                       const float* tab2f, const unsigned short* Bt,
                       unsigned short* parth, hipStream_t stream) {
    if (SPLIT == 16) att_gemm<8><<<64 * 16, 256, 0, stream>>>(bits, rowco, tab2f, Bt, parth);
    else             att_gemm<16><<<64 * 8, 256, 0, stream>>>(bits, rowco, tab2f, Bt, parth);
}

static void launch_frp(int SPLIT, const unsigned short* parth, const unsigned short* Bt,
                       const float* av, float* f1f2, unsigned short* Cbt, hipStream_t stream) {
    if (SPLIT == 16) fused_rp<16><<<256, 256, 0, stream>>>(parth, Bt, av, f1f2, Cbt);
    else             fused_rp<8><<<256, 256, 0, stream>>>(parth, Bt, av, f1f2, Cbt);
}

static void launch_rout(int SPLIT, const unsigned short* parth, float* outf, hipStream_t stream) {
    if (SPLIT == 16) reduce_out<16><<<512, 256, 0, stream>>>(parth, outf);
    else             reduce_out<8><<<512, 256, 0, stream>>>(parth, outf);
}

extern "C" void kernel_launch(void* const* d_in, const int* in_sizes, int n_in,
                              void* d_out, int out_size, void* d_ws, size_t ws_size,
                              hipStream_t stream) {
    const float* input = (const float*)d_in[0];
    const int*   adj   = (const int*)d_in[1];
    const float* W0    = (const float*)d_in[2];
    const float* W1    = (const float*)d_in[3];
    const float* a1    = (const float*)d_in[4];
    const float* W2    = (const float*)d_in[5];
    const float* a2    = (const float*)d_in[6];
    const float* W3    = (const float*)d_in[7];
    const float* a3    = (const float*)d_in[8];
    float* out = (float*)d_out;
    char* ws = (char*)d_ws;

    unsigned long long* bits = (unsigned long long*)(ws);                 // 2 MB
    unsigned short* h0   = (unsigned short*)(ws + (2u << 20));            // 2 MB (bf16 input proj)
    unsigned short* h1   = (unsigned short*)(ws + (4u << 20));            // 2 MB
    unsigned short* Whbt = (unsigned short*)(ws + (6u << 20));            // 2 MB
    unsigned short* Wbt  = (unsigned short*)(ws + (8u << 20));            // 512 KB
    float*  f1f2  = (float*)(ws + (9u << 20));                            // 3 layers x 32 KB
    float4* rowco = (float4*)(ws + (10u << 20));                          // 64 KB
    float2* tab2  = (float2*)(ws + (10u << 20) + (256u << 10));           // 32 KB
    unsigned short* parth = (unsigned short*)(ws + (13u << 20));          // 2 MB * SPLIT (fp16)

    const size_t base = 13u << 20;
    int SPLIT = (base + 16u * (2u << 20) <= ws_size) ? 16 : 8;

    float* f1f2_l[3] = { f1f2, f1f2 + 8192, f1f2 + 16384 };

    setup<<<5124, 256, 0, stream>>>(adj, input, W0, W1, W2, W3, bits, h0, Wbt, f1f2);

    // h = input @ W0 -> h1 (row-major bf16)
    proj_gemm<<<512, 256, 0, stream>>>(h0, Wbt + 0 * 65536, nullptr, nullptr, nullptr, h1);

    // layer 1: proj (Wh1 = h1 @ W1 -> Whbt + f1f2), rowcoef, att
    proj_gemm<<<512, 256, 0, stream>>>(h1, Wbt + 1 * 65536, a1, f1f2_l[0], Whbt, nullptr);
    rowcoef<<<512, 256, 0, stream>>>(bits, f1f2_l[0], rowco, tab2);
    launch_att(SPLIT, bits, rowco, (const float*)tab2, Whbt, parth, stream);

    // layer 2: fused reduce+proj (h2 never hits global), rowcoef, att
    launch_frp(SPLIT, parth, Wbt + 2 * 65536, a2, f1f2_l[1], Whbt, stream);
    rowcoef<<<512, 256, 0, stream>>>(bits, f1f2_l[1], rowco, tab2);
    launch_att(SPLIT, bits, rowco, (const float*)tab2, Whbt, parth, stream);

    // layer 3: fused reduce+proj, rowcoef, att, final out
    launch_frp(SPLIT, parth, Wbt + 3 * 65536, a3, f1f2_l[2], Whbt, stream);
    rowcoef<<<512, 256, 0, stream>>>(bits, f1f2_l[2], rowco, tab2);
    launch_att(SPLIT, bits, rowco, (const float*)tab2, Whbt, parth, stream);
    launch_rout(SPLIT, parth, out, stream);
}

// Round 12
// 276.564 us; speedup vs baseline: 1.0027x; 1.0027x over previous
//
#include <hip/hip_runtime.h>
#include <hip/hip_bf16.h>
#include <hip/hip_fp16.h>
#include <cstdint>
#include <cstddef>

#define NN 4096
#define FD 256
#define WPR 64  // 64-bit words per adjacency row

typedef __attribute__((ext_vector_type(8))) unsigned short ushort8v;
typedef __attribute__((ext_vector_type(4))) unsigned short ushort4v;
typedef __attribute__((ext_vector_type(8))) short short8;
typedef __attribute__((ext_vector_type(4))) float float4v;

#define C1 30.0f
#define C2 0.3f    // 0.01 * C1

static __device__ __forceinline__ unsigned short f2bf(float x) {
    union { float f; unsigned int u; } v; v.f = x;
    unsigned int r = v.u + 0x7FFFu + ((v.u >> 16) & 1u);
    return (unsigned short)(r >> 16);
}

static __device__ __forceinline__ short8 as_s8(ushort8v v) {
    union { ushort8v u; short8 s; } x; x.u = v; return x.s;
}

// async 16B/lane global -> LDS DMA (wave-uniform LDS base + lane*16)
static __device__ __forceinline__ void gl_lds16(const unsigned short* g, unsigned short* l) {
    __builtin_amdgcn_global_load_lds(
        (const __attribute__((address_space(1))) unsigned int*)g,
        (__attribute__((address_space(3))) unsigned int*)l,
        16, 0, 0);
}

// ---------------- fused setup: pack adj + cvt input + cvt weights + zero f1f2 ----------------
__global__ __launch_bounds__(256) void setup(const int* __restrict__ adj,
                                             const float* __restrict__ input,
                                             const float* __restrict__ W0, const float* __restrict__ W1,
                                             const float* __restrict__ W2, const float* __restrict__ W3,
                                             unsigned long long* __restrict__ bits,
                                             unsigned short* __restrict__ hb,
                                             unsigned short* __restrict__ Wbt,
                                             float* __restrict__ f1f2) {
    const int b = blockIdx.x;
    const int t = threadIdx.x;
    if (b < 4096) {
        const int wave = t >> 6, lane = t & 63;
        const int* arow = adj + (size_t)b * NN;
        #pragma unroll
        for (int it = 0; it < NN / 256; ++it) {
            int j = it * 256 + wave * 64 + lane;
            unsigned long long m = __ballot(arow[j] > 0);
            if (lane == 0) bits[(size_t)b * WPR + (it * 4 + wave)] = m;
        }
        hb[(size_t)b * 256 + t] = f2bf(input[(size_t)b * 256 + t]);
    } else if (b < 5120) {
        int idx = (b - 4096) * 256 + t;
        int mat = idx >> 16;
        int within = idx & 65535;
        int n = within >> 8, k = within & 255;
        const float* W = (mat == 0) ? W0 : (mat == 1) ? W1 : (mat == 2) ? W2 : W3;
        Wbt[idx] = f2bf(W[k * 256 + n]);
    } else {
        #pragma unroll
        for (int i = 0; i < 24; ++i) {
            int pos = i * 1024 + (b - 5120) * 256 + t;
            f1f2[pos] = 0.f;
        }
    }
}

// ---------------- projection GEMM: 32x64 tiles, grid 512 (layers 0/1 only) ----------------
__global__ __launch_bounds__(256) void proj_gemm(const unsigned short* __restrict__ A,
                                                 const unsigned short* __restrict__ Bt,
                                                 const float* __restrict__ av,
                                                 float* __restrict__ f1f2,
                                                 unsigned short* __restrict__ Cbt,
                                                 unsigned short* __restrict__ Crow) {
    const int t = threadIdx.x;
    const int bm = blockIdx.x >> 2, bn = blockIdx.x & 3;
    const int m0 = bm * 32, n0 = bn * 64;
    __shared__ unsigned short As[32 * 264];
    __shared__ unsigned short Bs[64 * 264];
    const int lane = t & 63, wave = t >> 6;
    const int wm = (wave >> 1) * 16, wn = (wave & 1) * 32;
    const int g = lane >> 4, ml = lane & 15;
    {
        int ar = t >> 3, ac0 = (t & 7) * 8;
        #pragma unroll
        for (int i = 0; i < 4; ++i) {
            int col = ac0 + i * 64;
            *(ushort8v*)&As[ar * 264 + col] = *(const ushort8v*)&A[(size_t)(m0 + ar) * 256 + col];
        }
        int br = t >> 2, bc0 = (t & 3) * 8;
        #pragma unroll
        for (int i = 0; i < 8; ++i) {
            int col = bc0 + i * 32;
            *(ushort8v*)&Bs[br * 264 + col] = *(const ushort8v*)&Bt[(size_t)(n0 + br) * 256 + col];
        }
    }
    __syncthreads();
    float4v acc[2] = {{0.f,0.f,0.f,0.f},{0.f,0.f,0.f,0.f}};
    #pragma unroll
    for (int kk = 0; kk < 256; kk += 32) {
        const int kc = kk + g * 8;
        short8 a = as_s8(*(const ushort8v*)&As[(wm + ml) * 264 + kc]);
        #pragma unroll
        for (int fn = 0; fn < 2; ++fn) {
            short8 b = as_s8(*(const ushort8v*)&Bs[(wn + fn * 16 + ml) * 264 + kc]);
            acc[fn] = __builtin_amdgcn_mfma_f32_16x16x32_bf16(a, b, acc[fn], 0, 0, 0);
        }
    }

    const int rb = wm + g * 4;
    if (Crow) {
        #pragma unroll
        for (int fn = 0; fn < 2; ++fn)
            #pragma unroll
            for (int r = 0; r < 4; ++r)
                Crow[(size_t)(m0 + rb + r) * 256 + n0 + wn + fn * 16 + ml] = f2bf(acc[fn][r]);
    }

    if (f1f2) {
        float a1c[2], a2c[2];
        #pragma unroll
        for (int fn = 0; fn < 2; ++fn) {
            a1c[fn] = av[n0 + wn + fn * 16 + ml];
            a2c[fn] = av[256 + n0 + wn + fn * 16 + ml];
        }
        #pragma unroll
        for (int r = 0; r < 4; ++r) {
            float s1 = acc[0][r] * a1c[0] + acc[1][r] * a1c[1];
            float s2 = acc[0][r] * a2c[0] + acc[1][r] * a2c[1];
            #pragma unroll
            for (int off = 1; off < 16; off <<= 1) {
                s1 += __shfl_xor(s1, off, 64);
                s2 += __shfl_xor(s2, off, 64);
            }
            if (ml == 0) {
                int row = m0 + rb + r;
                atomicAdd(&f1f2[row], s1);
                atomicAdd(&f1f2[4096 + row], s2);
            }
        }
    }

    if (Cbt) {
        unsigned short* T = As;
        __syncthreads();
        #pragma unroll
        for (int fn = 0; fn < 2; ++fn)
            #pragma unroll
            for (int r = 0; r < 4; ++r)
                T[(wn + fn * 16 + ml) * 40 + rb + r] = f2bf(acc[fn][r]);
        __syncthreads();
        const int tr = t >> 2, tc = (t & 3) * 8;
        *(ushort8v*)&Cbt[(size_t)(n0 + tr) * 4096 + m0 + tc] = *(const ushort8v*)&T[tr * 40 + tc];
    }
}

// ---------------- per-row coefficients + global exp tables ----------------
__global__ __launch_bounds__(256) void rowcoef(const unsigned long long* __restrict__ bits,
                                               const float* __restrict__ f1f2,
                                               float4* __restrict__ rowco,
                                               float2* __restrict__ tab2g) {
    __shared__ float2 tl[4096];
    const int t = threadIdx.x;
    const float* f2p = f1f2 + 4096;
    #pragma unroll
    for (int i = 0; i < 16; ++i) {
        float v = f2p[i * 256 + t];
        float2 pr = make_float2(__expf(v - C1), __expf(0.01f * v - C2));
        tl[i * 256 + t] = pr;
        if (blockIdx.x == 0) tab2g[i * 256 + t] = pr;
    }
    __syncthreads();
    const int lane = t & 63, wave = t >> 6;
    for (int rr = 0; rr < 2; ++rr) {
        const int row = blockIdx.x * 8 + wave * 2 + rr;
        const unsigned long long wl = bits[(size_t)row * WPR + lane];
        const float f1r = f1f2[row];
        const float th = __expf(-f1r - C1);
        float mx = 0.f, S1 = 0.f, S2 = 0.f;
        #pragma unroll 16
        for (int b = 0; b < 64; ++b) {
            unsigned long long w = __shfl(wl, b, 64);
            bool bit = (w >> lane) & 1ULL;
            float2 v = tl[b * 64 + lane];
            float ebm = bit ? v.x : 0.f;
            mx = fmaxf(mx, ebm);
            bool cond = v.x > th;
            S1 += (bit && cond)  ? v.x : 0.f;
            S2 += (bit && !cond) ? v.y : 0.f;
        }
        #pragma unroll
        for (int off = 1; off < 64; off <<= 1) {
            mx = fmaxf(mx, __shfl_xor(mx, off, 64));
            S1 += __shfl_xor(S1, off, 64);
            S2 += __shfl_xor(S2, off, 64);
        }
        if (lane == 0) {
            float M  = C1 + __logf(mx);
            float fm_ = f1r + M;
            float m  = fm_ > 0.f ? fm_ : 0.01f * fm_;    // lrelu
            float alpha = __expf(fminf(f1r + C1 - m, 60.f));
            float gamma = __expf(fminf(0.01f * (f1r + C1) - m, 60.f));
            float inv = 1.0f / (alpha * S1 + gamma * S2);
            rowco[row] = make_float4(alpha * inv, gamma * inv, th, 0.f);
        }
    }
}

// ---------------- attention GEMM v12: B staged via async global_load_lds DMA ----------------
// Bs layout [128][32] (DMA-native). 1 barrier/step; DMA + tab prefetch issued a step ahead.
template<int NSTEPS>
__global__ __launch_bounds__(256, 3) void att_gemm(const unsigned long long* __restrict__ bits,
                                                   const float4* __restrict__ rowco,
                                                   const float* __restrict__ tab2f,
                                                   const unsigned short* __restrict__ Bt,  // Whbt [256][4096]
                                                   unsigned short* __restrict__ parth) {
    const int t = threadIdx.x;
    const int bm = blockIdx.x & 31;
    const int bn = (blockIdx.x >> 5) & 1;
    const int ks = blockIdx.x >> 6;
    const int m0 = bm * 128, n0 = bn * 128;
    const int k0 = ks * (NSTEPS * 32);
    __shared__ unsigned short Bs[2][128 * 32];   // 2 x 8 KB, unpadded (DMA layout)
    const int lane = t & 63, wave = t >> 6;
    const int g = lane >> 4, ml = lane & 15;

    // DMA mapping: instr j, wave w, lane l -> LDS row j*64 + w*16 + (l>>2), col (l&3)*8
    const int drow = lane >> 2, dcol = (lane & 3) * 8;
    const unsigned short* dsrc0 = Bt + (size_t)(n0 + wave * 16 + drow) * 4096 + dcol;
    const unsigned short* dsrc1 = dsrc0 + (size_t)64 * 4096;
    unsigned short* dst0 = &Bs[0][wave * 512];
    unsigned short* dst1 = &Bs[0][2048 + wave * 512];
    unsigned short* dst0b = &Bs[1][wave * 512];
    unsigned short* dst1b = &Bs[1][2048 + wave * 512];

    float pA[2], pG[2];
    unsigned long long wpre[2][NSTEPS / 2];
    #pragma unroll
    for (int fm = 0; fm < 2; ++fm) {
        int row = m0 + wave * 32 + fm * 16 + ml;
        float4 rc = rowco[row];
        pA[fm] = rc.x; pG[fm] = rc.y;
        const unsigned long long* brow = bits + (size_t)row * WPR + (k0 >> 6);
        #pragma unroll
        for (int w = 0; w < NSTEPS / 2; ++w) wpre[fm][w] = brow[w];
    }

    float4v acc[2][8];
    #pragma unroll
    for (int i = 0; i < 2; ++i)
        #pragma unroll
        for (int j = 0; j < 8; ++j) acc[i][j] = (float4v){0.f, 0.f, 0.f, 0.f};

    // prologue: DMA step0 into buf0; tab step0 into regs
    float4v tq0, tq1, tq2, tq3;
    {
        gl_lds16(dsrc0 + k0, dst0);
        gl_lds16(dsrc1 + k0, dst1);
        const float4v* q = (const float4v*)&tab2f[2 * (k0 + g * 8)];
        tq0 = q[0]; tq1 = q[1]; tq2 = q[2]; tq3 = q[3];
    }
    __syncthreads();

    #pragma unroll
    for (int i = 0; i < NSTEPS; ++i) {
        const int kk = k0 + i * 32;
        const int p = i & 1;
        // issue next-step DMA + tab prefetch (lands during this step's compute)
        float4v nt0, nt1, nt2, nt3;
        if (i + 1 < NSTEPS) {
            gl_lds16(dsrc0 + kk + 32, p ? dst0 : dst0b);
            gl_lds16(dsrc1 + kk + 32, p ? dst1 : dst1b);
            const float4v* q = (const float4v*)&tab2f[2 * (kk + 32 + g * 8)];
            nt0 = q[0]; nt1 = q[1]; nt2 = q[2]; nt3 = q[3];
        }
        // A-gen: pure reg math
        const int sh = (i & 1) * 32 + g * 8;
        short8 afr[2];
        #pragma unroll
        for (int fm = 0; fm < 2; ++fm) {
            unsigned int wh = (unsigned int)(wpre[fm][i >> 1] >> sh);
            ushort8v af;
            #pragma unroll
            for (int jj = 0; jj < 4; ++jj) {
                float4v v = (jj == 0) ? tq0 : (jj == 1) ? tq1 : (jj == 2) ? tq2 : tq3;
                float x0 = fmaxf(pA[fm] * v[0], pG[fm] * v[1]);
                float x1 = fmaxf(pA[fm] * v[2], pG[fm] * v[3]);
                x0 = ((wh >> (2 * jj)) & 1u)     ? x0 : 0.f;
                x1 = ((wh >> (2 * jj + 1)) & 1u) ? x1 : 0.f;
                union { __hip_bfloat162 b2; unsigned int u; } cv;
                cv.b2 = __float22bfloat162_rn(make_float2(x0, x1));
                ((unsigned int*)&af)[jj] = cv.u;
            }
            afr[fm] = as_s8(af);
        }
        // MFMA from LDS B (row stride 32)
        #pragma unroll
        for (int fn = 0; fn < 8; ++fn) {
            short8 b = as_s8(*(const ushort8v*)&Bs[p][(fn * 16 + ml) * 32 + g * 8]);
            acc[0][fn] = __builtin_amdgcn_mfma_f32_16x16x32_bf16(afr[0], b, acc[0][fn], 0, 0, 0);
            acc[1][fn] = __builtin_amdgcn_mfma_f32_16x16x32_bf16(afr[1], b, acc[1][fn], 0, 0, 0);
        }
        // single barrier: drains next-step DMA, releases this buffer
        if (i + 1 < NSTEPS) {
            __syncthreads();
            tq0 = nt0; tq1 = nt1; tq2 = nt2; tq3 = nt3;
        }
    }

    // permuted coalesced fp16 epilogue
    unsigned short* pbase = parth + ((size_t)ks << 20) + (size_t)(bm * 2 + bn) * 16384;
    #pragma unroll
    for (int fm = 0; fm < 2; ++fm)
        #pragma unroll
        for (int fn = 0; fn < 8; ++fn) {
            ushort4v v4;
            #pragma unroll
            for (int r = 0; r < 4; ++r) {
                __half h = __float2half(acc[fm][fn][r]);
                v4[r] = *(unsigned short*)&h;
            }
            *(ushort4v*)&pbase[((wave * 16 + fm * 8 + fn) * 64 + lane) * 4] = v4;
        }
}

// ---------------- fused reduce(partials)+ELU -> h in LDS -> proj GEMM -> Whbt + f1f2 ----------------
template<int NS>
__global__ __launch_bounds__(256) void fused_rp(const unsigned short* __restrict__ parth,
                                                const unsigned short* __restrict__ Bt,   // Wbt [256n][256k]
                                                const float* __restrict__ av,            // attention vec [512]
                                                float* __restrict__ f1f2,
                                                unsigned short* __restrict__ Cbt) {      // Whbt [256][4096]
    const int t = threadIdx.x;
    const int m0 = blockIdx.x * 16;
    __shared__ unsigned short hA[16 * 280];
    __shared__ unsigned short T[256 * 24];

    const int bmP = m0 >> 7;
    const int wavea = (m0 >> 5) & 3;
    const int fmP = (m0 >> 4) & 1;
    const int bn = t >> 7, fnc = (t >> 4) & 7;
    const int widx = wavea * 16 + fmP * 8 + fnc;
    const size_t cbase = (size_t)(bmP * 2 + bn) * 16384 + (size_t)widx * 256 + (t & 15) * 16;
    float s[16];
    #pragma unroll
    for (int e = 0; e < 16; ++e) s[e] = 0.f;
    #pragma unroll
    for (int sp = 0; sp < NS; ++sp) {
        const unsigned short* p = &parth[((size_t)sp << 20) + cbase];
        ushort8v v0 = *(const ushort8v*)p;
        ushort8v v1 = *(const ushort8v*)(p + 8);
        #pragma unroll
        for (int e = 0; e < 8; ++e) {
            unsigned short u0 = v0[e], u1 = v1[e];
            s[e]     += __half2float(*(__half*)&u0);
            s[8 + e] += __half2float(*(__half*)&u1);
        }
    }
    const int gq = (t & 15) >> 2;
    const int colb = bn * 128 + fnc * 16 + (t & 3) * 4;
    #pragma unroll
    for (int r = 0; r < 4; ++r) {
        ushort4v w4;
        #pragma unroll
        for (int c = 0; c < 4; ++c) {
            float x = s[c * 4 + r];
            x = x > 0.f ? x : (__expf(x) - 1.f);
            w4[c] = f2bf(x);
        }
        *(ushort4v*)&hA[(gq * 4 + r) * 280 + colb] = w4;
    }
    __syncthreads();

    const int lane = t & 63, wave = t >> 6;
    const int g = lane >> 4, ml = lane & 15;
    float4v acc[4] = {{0.f,0.f,0.f,0.f},{0.f,0.f,0.f,0.f},{0.f,0.f,0.f,0.f},{0.f,0.f,0.f,0.f}};
    #pragma unroll
    for (int kk = 0; kk < 256; kk += 32) {
        short8 a = as_s8(*(const ushort8v*)&hA[ml * 280 + kk + g * 8]);
        #pragma unroll
        for (int fn = 0; fn < 4; ++fn) {
            short8 b = as_s8(*(const ushort8v*)&Bt[(size_t)(wave * 64 + fn * 16 + ml) * 256 + kk + g * 8]);
            acc[fn] = __builtin_amdgcn_mfma_f32_16x16x32_bf16(a, b, acc[fn], 0, 0, 0);
        }
    }

    {
        float a1c[4], a2c[4];
        #pragma unroll
        for (int fn = 0; fn < 4; ++fn) {
            int col = wave * 64 + fn * 16 + ml;
            a1c[fn] = av[col];
            a2c[fn] = av[256 + col];
        }
        #pragma unroll
        for (int r = 0; r < 4; ++r) {
            float s1 = acc[0][r] * a1c[0] + acc[1][r] * a1c[1] + acc[2][r] * a1c[2] + acc[3][r] * a1c[3];
            float s2 = acc[0][r] * a2c[0] + acc[1][r] * a2c[1] + acc[2][r] * a2c[2] + acc[3][r] * a2c[3];
            #pragma unroll
            for (int off = 1; off < 16; off <<= 1) {
                s1 += __shfl_xor(s1, off, 64);
                s2 += __shfl_xor(s2, off, 64);
            }
            if (ml == 0) {
                int row = m0 + g * 4 + r;
                atomicAdd(&f1f2[row], s1);
                atomicAdd(&f1f2[4096 + row], s2);
            }
        }
    }

    #pragma unroll
    for (int fn = 0; fn < 4; ++fn) {
        int nl = wave * 64 + fn * 16 + ml;
        ushort4v v4;
        #pragma unroll
        for (int r = 0; r < 4; ++r) v4[r] = f2bf(acc[fn][r]);
        *(ushort4v*)&T[nl * 24 + g * 4] = v4;
    }
    __syncthreads();
    {
        const int tn = t >> 1, half = t & 1;
        #pragma unroll
        for (int pass = 0; pass < 2; ++pass) {
            int n = pass * 128 + tn;
            *(ushort8v*)&Cbt[(size_t)n * 4096 + m0 + half * 8] = *(const ushort8v*)&T[n * 24 + half * 8];
        }
    }
}

// ---------------- final reduce: partials -> ELU -> fp32 out ----------------
template<int NS>
__global__ __launch_bounds__(256) void reduce_out(const unsigned short* __restrict__ parth,
                                                  float* __restrict__ outf) {
    const int flat = (blockIdx.x * 256 + threadIdx.x) * 8;
    float s[8] = {0.f, 0.f, 0.f, 0.f, 0.f, 0.f, 0.f, 0.f};
    #pragma unroll
    for (int sp = 0; sp < NS; ++sp) {
        ushort8v v = *(const ushort8v*)&parth[((size_t)sp << 20) + flat];
        #pragma unroll
        for (int j = 0; j < 8; ++j) {
            unsigned short u = v[j];
            s[j] += __half2float(*(__half*)&u);
        }
    }
    const int tile  = flat >> 14;
    const int inner = flat & 16383;
    const int widx = inner >> 8;
    const int ls   = (inner >> 2) & 63;
    const int bm = tile >> 1, bn = tile & 1;
    const int wavea = widx >> 4, fm = (widx >> 3) & 1, fn = widx & 7;
    const int g = ls >> 4, ml = ls & 15;
    const int row0 = bm * 128 + wavea * 32 + fm * 16 + g * 4;
    const int col  = bn * 128 + fn * 16 + ml;
    #pragma unroll
    for (int r = 0; r < 4; ++r) {
        float x0 = s[r];
        float x1 = s[4 + r];
        x0 = x0 > 0.f ? x0 : (__expf(x0) - 1.f);
        x1 = x1 > 0.f ? x1 : (__expf(x1) - 1.f);
        *(float2*)&outf[(size_t)(row0 + r) * 256 + col] = make_float2(x0, x1);
    }
}

static void launch_att(int SPLIT, const unsigned long long* bits, const float4* rowco,
                       const float* tab2f, const unsigned short* Bt,
                       unsigned short* parth, hipStream_t stream) {
    if (SPLIT == 16) att_gemm<8><<<64 * 16, 256, 0, stream>>>(bits, rowco, tab2f, Bt, parth);
    else             att_gemm<16><<<64 * 8, 256, 0, stream>>>(bits, rowco, tab2f, Bt, parth);
}

static void launch_frp(int SPLIT, const unsigned short* parth, const unsigned short* Bt,
                       const float* av, float* f1f2, unsigned short* Cbt, hipStream_t stream) {
    if (SPLIT == 16) fused_rp<16><<<256, 256, 0, stream>>>(parth, Bt, av, f1f2, Cbt);
    else             fused_rp<8><<<256, 256, 0, stream>>>(parth, Bt, av, f1f2, Cbt);
}

static void launch_rout(int SPLIT, const unsigned short* parth, float* outf, hipStream_t stream) {
    if (SPLIT == 16) reduce_out<16><<<512, 256, 0, stream>>>(parth, outf);
    else             reduce_out<8><<<512, 256, 0, stream>>>(parth, outf);
}

extern "C" void kernel_launch(void* const* d_in, const int* in_sizes, int n_in,
                              void* d_out, int out_size, void* d_ws, size_t ws_size,
                              hipStream_t stream) {
    const float* input = (const float*)d_in[0];
    const int*   adj   = (const int*)d_in[1];
    const float* W0    = (const float*)d_in[2];
    const float* W1    = (const float*)d_in[3];
    const float* a1    = (const float*)d_in[4];
    const float* W2    = (const float*)d_in[5];
    const float* a2    = (const float*)d_in[6];
    const float* W3    = (const float*)d_in[7];
    const float* a3    = (const float*)d_in[8];
    float* out = (float*)d_out;
    char* ws = (char*)d_ws;

    unsigned long long* bits = (unsigned long long*)(ws);                 // 2 MB
    unsigned short* h0   = (unsigned short*)(ws + (2u << 20));            // 2 MB
    unsigned short* h1   = (unsigned short*)(ws + (4u << 20));            // 2 MB
    unsigned short* Whbt = (unsigned short*)(ws + (6u << 20));            // 2 MB
    unsigned short* Wbt  = (unsigned short*)(ws + (8u << 20));            // 512 KB
    float*  f1f2  = (float*)(ws + (9u << 20));                            // 3 layers x 32 KB
    float4* rowco = (float4*)(ws + (10u << 20));                          // 64 KB
    float2* tab2  = (float2*)(ws + (10u << 20) + (256u << 10));           // 32 KB
    unsigned short* parth = (unsigned short*)(ws + (13u << 20));          // 2 MB * SPLIT (fp16)

    const size_t base = 13u << 20;
    int SPLIT = (base + 16u * (2u << 20) <= ws_size) ? 16 : 8;

    float* f1f2_l[3] = { f1f2, f1f2 + 8192, f1f2 + 16384 };

    setup<<<5124, 256, 0, stream>>>(adj, input, W0, W1, W2, W3, bits, h0, Wbt, f1f2);

    // h = input @ W0 -> h1 (row-major bf16)
    proj_gemm<<<512, 256, 0, stream>>>(h0, Wbt + 0 * 65536, nullptr, nullptr, nullptr, h1);

    // layer 1
    proj_gemm<<<512, 256, 0, stream>>>(h1, Wbt + 1 * 65536, a1, f1f2_l[0], Whbt, nullptr);
    rowcoef<<<512, 256, 0, stream>>>(bits, f1f2_l[0], rowco, tab2);
    launch_att(SPLIT, bits, rowco, (const float*)tab2, Whbt, parth, stream);

    // layer 2
    launch_frp(SPLIT, parth, Wbt + 2 * 65536, a2, f1f2_l[1], Whbt, stream);
    rowcoef<<<512, 256, 0, stream>>>(bits, f1f2_l[1], rowco, tab2);
    launch_att(SPLIT, bits, rowco, (const float*)tab2, Whbt, parth, stream);

    // layer 3
    launch_frp(SPLIT, parth, Wbt + 3 * 65536, a3, f1f2_l[2], Whbt, stream);
    rowcoef<<<512, 256, 0, stream>>>(bits, f1f2_l[2], rowco, tab2);
    launch_att(SPLIT, bits, rowco, (const float*)tab2, Whbt, parth, stream);
    launch_rout(SPLIT, parth, out, stream);
}